// Round 11
// baseline (5440.834 us; speedup 1.0000x reference)
//
#include <hip/hip_runtime.h>
#include <stdint.h>
#include <stddef.h>

#define TT 1024
#define BB 64
#define HH 1024
#define II 1024

typedef __attribute__((ext_vector_type(8))) short s16x8;
typedef __attribute__((ext_vector_type(4))) float f32x4;
typedef __attribute__((ext_vector_type(2))) unsigned u32x2;

// ---- workspace layout (bytes) ---- (r5/r9-proven footprint, <= 266240)
// 512  : flags[4][64] u32  (per group 256 B: one word PER WAVE sl*4+wid)
// 4096 : ring: group*65536 + slot*32768 + row*2048 + feat*2
//        (4 groups, 2 slots, 16 rows, 1024 bf16 features)
#define WS_FLAGS 512
#define WS_RING  4096

static __device__ __forceinline__ unsigned short f2bf(float f) {
    union { float f; unsigned int u; } v; v.f = f;
    return (unsigned short)((v.u + 0x7fffu + ((v.u >> 16) & 1u)) >> 16);
}

static __device__ __forceinline__ s16x8 pack8(float4 a, float4 b) {
    s16x8 v;
    v[0] = (short)f2bf(a.x); v[1] = (short)f2bf(a.y);
    v[2] = (short)f2bf(a.z); v[3] = (short)f2bf(a.w);
    v[4] = (short)f2bf(b.x); v[5] = (short)f2bf(b.y);
    v[6] = (short)f2bf(b.z); v[7] = (short)f2bf(b.w);
    return v;
}

static __device__ __forceinline__ f32x4 zero4() {
    f32x4 v = {0.f, 0.f, 0.f, 0.f};
    return v;
}

// fast tanh: (p-1)/(p+1), p = e^{2x} via v_exp_f32; clamp keeps p finite.
// abs error ~1e-7 -- negligible vs the 0.0156 bf16-ring error floor.
static __device__ __forceinline__ float tanh_fast(float x) {
    float s = fminf(fmaxf(x, -9.0f), 9.0f);
    float p = __builtin_amdgcn_exp2f(s * 2.885390081777927f);  // e^{2s}
    return (p - 1.0f) * __builtin_amdgcn_rcpf(p + 1.0f);
}

// Device-coherent-point access (r3/r5/r9/r10-proven): sc0 sc1 = bypass L1+L2.
static __device__ __forceinline__ s16x8 ld16_sc01(const void* p) {
    s16x8 v;
    asm volatile("global_load_dwordx4 %0, %1, off sc0 sc1" : "=v"(v) : "v"(p));
    return v;
}
static __device__ __forceinline__ unsigned ld4_sc01_wait(const void* p) {
    unsigned v;
    asm volatile("global_load_dword %0, %1, off sc0 sc1\n\ts_waitcnt vmcnt(0)"
                 : "=v"(v) : "v"(p) : "memory");
    return v;
}
static __device__ __forceinline__ void st8_sc01(void* p, u32x2 v) {
    asm volatile("global_store_dwordx2 %0, %1, off sc0 sc1" :: "v"(p), "v"(v) : "memory");
}

// ---------------------------------------------------------------------------
// Kernel 0: zero the control region (flags) each launch.
// ---------------------------------------------------------------------------
__global__ void init_ws(unsigned int* w) {
    for (int i = threadIdx.x; i < 640; i += 256)
        __hip_atomic_store(&w[i], 0u, __ATOMIC_RELAXED, __HIP_MEMORY_SCOPE_AGENT);
}

// ---------------------------------------------------------------------------
// Kernel 1: xw = x @ W_ih^T + b_ih + b_hh -> d_out states area (unchanged).
// ---------------------------------------------------------------------------
__global__ __launch_bounds__(256, 2) void xw_gemm(
    const float* __restrict__ X,
    const float* __restrict__ Wih,
    const float* __restrict__ bih,
    const float* __restrict__ bhh,
    float* __restrict__ out)
{
    __shared__ unsigned short As[128 * 64];
    __shared__ unsigned short Bs[128 * 64];

    const int tid  = threadIdx.x;
    const int lane = tid & 63;
    const int wid  = tid >> 6;
    const int bm = blockIdx.x >> 3;
    const int bn = blockIdx.x & 7;
    const size_t m0 = (size_t)bm * 128;
    const int n0 = bn * 128;
    const int wm = (wid >> 1) * 64;
    const int wn = (wid & 1) * 64;

    f32x4 acc[4][4];
#pragma unroll
    for (int i = 0; i < 4; ++i)
#pragma unroll
        for (int jj = 0; jj < 4; ++jj) acc[i][jj] = zero4();

    const int srow  = tid >> 1;
    const int shalf = tid & 1;
    const float* xp = X   + (m0 + srow) * (size_t)II + shalf * 32;
    const float* wp = Wih + (size_t)(n0 + srow) * II + shalf * 32;

    for (int kt = 0; kt < II / 64; ++kt) {
#pragma unroll
        for (int i = 0; i < 4; ++i) {
            float4 a0 = *(const float4*)(xp + i * 8);
            float4 a1 = *(const float4*)(xp + i * 8 + 4);
            float4 b0 = *(const float4*)(wp + i * 8);
            float4 b1 = *(const float4*)(wp + i * 8 + 4);
            const int c = shalf * 4 + i;
            const int cw = (c ^ (srow & 7)) << 3;
            *(s16x8*)&As[srow * 64 + cw] = pack8(a0, a1);
            *(s16x8*)&Bs[srow * 64 + cw] = pack8(b0, b1);
        }
        __syncthreads();

#pragma unroll
        for (int kk = 0; kk < 2; ++kk) {
            s16x8 af[4], bf[4];
            const int cs = kk * 4 + (lane >> 4);
#pragma unroll
            for (int mi = 0; mi < 4; ++mi) {
                const int r = wm + mi * 16 + (lane & 15);
                af[mi] = *(const s16x8*)&As[r * 64 + ((cs ^ (r & 7)) << 3)];
            }
#pragma unroll
            for (int ni = 0; ni < 4; ++ni) {
                const int r = wn + ni * 16 + (lane & 15);
                bf[ni] = *(const s16x8*)&Bs[r * 64 + ((cs ^ (r & 7)) << 3)];
            }
#pragma unroll
            for (int mi = 0; mi < 4; ++mi)
#pragma unroll
                for (int ni = 0; ni < 4; ++ni)
                    acc[mi][ni] = __builtin_amdgcn_mfma_f32_16x16x32_bf16(
                        af[mi], bf[ni], acc[mi][ni], 0, 0, 0);
        }
        __syncthreads();
        xp += 64; wp += 64;
    }

#pragma unroll
    for (int ni = 0; ni < 4; ++ni) {
        const int col = n0 + wn + ni * 16 + (lane & 15);
        const float bias = bih[col] + bhh[col];
#pragma unroll
        for (int mi = 0; mi < 4; ++mi) {
            const size_t row = m0 + wm + mi * 16 + ((lane >> 4) << 2);
#pragma unroll
            for (int r = 0; r < 4; ++r)
                out[(row + r) * (size_t)HH + col] = acc[mi][ni][r] + bias;
        }
    }
}

#define KSTEP(ki, n) do { \
    asm volatile("s_waitcnt vmcnt(" #n ")" ::: "memory"); \
    __builtin_amdgcn_sched_barrier(0); \
    acc[0] = __builtin_amdgcn_mfma_f32_16x16x32_bf16(afr[0*8+(ki)], h8[ki], acc[0], 0, 0, 0); \
    acc[1] = __builtin_amdgcn_mfma_f32_16x16x32_bf16(afr[1*8+(ki)], h8[ki], acc[1], 0, 0, 0); \
    acc[2] = __builtin_amdgcn_mfma_f32_16x16x32_bf16(afr[2*8+(ki)], h8[ki], acc[2], 0, 0, 0); \
    acc[3] = __builtin_amdgcn_mfma_f32_16x16x32_bf16(afr[3*8+(ki)], h8[ki], acc[3], 0, 0, 0); \
} while (0)

// ---------------------------------------------------------------------------
// Kernel 2: persistent scan, K-SPLIT waves. 64 blocks x 256 thr (4 waves).
// 4 groups x 16 blocks; group owns batch rows [16g,16g+16); block = 64
// features. Wave wid handles k-quarter wid for ALL 4 m-tiles: W slice
// (64 feats x 256 k) in 128 VGPR/wave; ring B-fragments loaded DIRECTLY
// into registers (per-lane addresses == MFMA B-frag layout; no LDS tile,
// no stage barrier). Cross-wave k-reduction via small LDS buffer + ONE
// __syncthreads; wave wid owns m-tile wid's epilogue. Per-wave flags:
// relaxed agent atomic store after own vmcnt(0) (r3 primitive); poll all
// 64 via coalesced bypass dword loads (r10 primitive) => all waves done
// step t-1 incl staging => 2-slot ring WAR-safe.
// ---------------------------------------------------------------------------
__global__ __launch_bounds__(256, 1) void rnn_scan(
    const float* __restrict__ Whh,
    float* __restrict__ out,
    void* __restrict__ ws)
{
    __shared__ float Red[2 * 16 * 64 * 4];   // 32 KiB, dbuf k-partials

    const int tid  = threadIdx.x;
    const int lane = tid & 63;
    const int wid  = tid >> 6;
    const int g  = blockIdx.x >> 4;     // 0..3 batch group
    const int sl = blockIdx.x & 15;     // 0..15 feature slice (64 feats)

    const int kg = lane >> 4;           // k-subchunk within 32 / feat quarter
    const int bl = lane & 15;           // batch row within group / A feat row

    // ---- one-time: W A-frags for 4 m-tiles x k-quarter wid (128 VGPRs) ----
    // afr[m*8+ki]: m-tile m (feats sl*64+m*16), k = (wid*8+ki)*32 + kg*8.
    s16x8 afr[32];
#pragma unroll
    for (int m = 0; m < 4; ++m)
#pragma unroll
        for (int ki = 0; ki < 8; ++ki) {
            const float* wr = Whh + (size_t)(sl * 64 + m * 16 + bl) * HH
                            + (wid * 8 + ki) * 32 + kg * 8;
            afr[m * 8 + ki] = pack8(*(const float4*)wr, *(const float4*)(wr + 4));
        }

    unsigned* fl = (unsigned*)((char*)ws + WS_FLAGS) + g * 64;
    unsigned* myflag = fl + sl * 4 + wid;
    char* rg = (char*)ws + WS_RING + (size_t)g * 65536;

    // B-frag staging base: row bl, chunk wid*32 + kg (+4 per ki step)
    const char* const pb0 = rg + bl * 2048 + (wid * 32 + kg) * 16;  // slot 0
    const char* const pb1 = pb0 + 32768;                             // slot 1

    // output mapping (D = W*hr, m-tile wid): lane owns batch bl, feats f0..f0+3
    const int b  = g * 16 + bl;
    const int f0 = sl * 64 + wid * 16 + kg * 4;

    float hprev[4];

    // ---- t = 0: h = tanh(xw); hr_1 = 0.5*h -> slot 1; per-wave flag ----
    {
        const size_t idx = ((size_t)b * TT) * HH + f0;
        float4 xw4 = *(const float4*)(out + idx);
        float4 st;
        st.x = tanh_fast(xw4.x); st.y = tanh_fast(xw4.y);
        st.z = tanh_fast(xw4.z); st.w = tanh_fast(xw4.w);
        hprev[0] = st.x; hprev[1] = st.y; hprev[2] = st.z; hprev[3] = st.w;
        *(float4*)(out + idx) = st;
        u32x2 pk;
        pk[0] = (unsigned)f2bf(0.5f * st.x) | ((unsigned)f2bf(0.5f * st.y) << 16);
        pk[1] = (unsigned)f2bf(0.5f * st.z) | ((unsigned)f2bf(0.5f * st.w) << 16);
        st8_sc01(rg + 32768 + bl * 2048 + f0 * 2, pk);
    }
    asm volatile("s_waitcnt vmcnt(0)" ::: "memory");
    if (lane == 0)
        __hip_atomic_store(myflag, 1u, __ATOMIC_RELAXED, __HIP_MEMORY_SCOPE_AGENT);

#pragma unroll 1
    for (int t = 1; t < TT; ++t) {
        // ---- xw prefetch (cached; drained by the poll's vmcnt) ----
        const size_t xidx = ((size_t)b * TT + t) * HH + f0;
        float4 xw4 = *(const float4*)(out + xidx);

        // ---- poll all 64 per-wave flags (coalesced bypass, 4 lines) ----
        {
            const unsigned* myp = fl + lane;
            for (;;) {
                unsigned v = ld4_sc01_wait(myp);
                if (__all((int)(v >= (unsigned)t))) break;
                __builtin_amdgcn_s_sleep(1);
            }
            asm volatile("" ::: "memory");
            __builtin_amdgcn_sched_barrier(0);
        }

        // ---- stage k-quarter DIRECTLY into B-frag registers + MFMA ----
        const char* p = (t & 1) ? pb1 : pb0;
        s16x8 h8[8];
#pragma unroll
        for (int ki = 0; ki < 8; ++ki) h8[ki] = ld16_sc01(p + ki * 64);
        f32x4 acc[4];
#pragma unroll
        for (int i = 0; i < 4; ++i) acc[i] = zero4();
        KSTEP(0, 7); KSTEP(1, 6); KSTEP(2, 5); KSTEP(3, 4);
        KSTEP(4, 3); KSTEP(5, 2); KSTEP(6, 1); KSTEP(7, 0);

        // ---- cross-wave k-reduction: write 4 partials, barrier, sum ----
        float* rb = Red + (size_t)(t & 1) * 4096;
#pragma unroll
        for (int m = 0; m < 4; ++m)
            *(f32x4*)&rb[((wid * 4 + m) * 64 + lane) * 4] = acc[m];
        __syncthreads();
        f32x4 s4 = *(f32x4*)&rb[((0 * 4 + wid) * 64 + lane) * 4];
#pragma unroll
        for (int w2 = 1; w2 < 4; ++w2)
            s4 = s4 + *(f32x4*)&rb[((w2 * 4 + wid) * 64 + lane) * 4];

        // ---- epilogue (m-tile wid): tanh, states, ring, per-wave flag ----
        {
            float hn[4];
#pragma unroll
            for (int r = 0; r < 4; ++r)
                hn[r] = tanh_fast(s4[r] + ((const float*)&xw4)[r]);
            float4 st; st.x = hn[0]; st.y = hn[1]; st.z = hn[2]; st.w = hn[3];
            *(float4*)(out + xidx) = st;
            if (t == TT - 1) {
                *(float4*)(out + (size_t)BB * TT * HH + (size_t)b * HH + f0) = st;
            } else {
                u32x2 pk;
                pk[0] = (unsigned)f2bf(0.5f * (hn[0] + hprev[0])) |
                        ((unsigned)f2bf(0.5f * (hn[1] + hprev[1])) << 16);
                pk[1] = (unsigned)f2bf(0.5f * (hn[2] + hprev[2])) |
                        ((unsigned)f2bf(0.5f * (hn[3] + hprev[3])) << 16);
                char* rw = rg + (size_t)((t + 1) & 1) * 32768;
                st8_sc01(rw + bl * 2048 + f0 * 2, pk);
            }
#pragma unroll
            for (int r = 0; r < 4; ++r) hprev[r] = hn[r];
        }
        if (t < TT - 1) {
            asm volatile("s_waitcnt vmcnt(0)" ::: "memory");
            if (lane == 0)
                __hip_atomic_store(myflag, (unsigned)(t + 1),
                                   __ATOMIC_RELAXED, __HIP_MEMORY_SCOPE_AGENT);
        }
    }
}

// ---------------------------------------------------------------------------
extern "C" void kernel_launch(void* const* d_in, const int* in_sizes, int n_in,
                              void* d_out, int out_size, void* d_ws, size_t ws_size,
                              hipStream_t stream)
{
    const float* X   = (const float*)d_in[0];
    const float* Wih = (const float*)d_in[1];
    const float* Whh = (const float*)d_in[2];
    const float* bih = (const float*)d_in[3];
    const float* bhh = (const float*)d_in[4];
    float* out = (float*)d_out;

    init_ws<<<dim3(1), dim3(256), 0, stream>>>((unsigned int*)d_ws);
    xw_gemm<<<dim3(4096), dim3(256), 0, stream>>>(X, Wih, bih, bhh, out);
    rnn_scan<<<dim3(64), dim3(256), 0, stream>>>(Whh, out, d_ws);
}

// Round 12
// 3600.447 us; speedup vs baseline: 1.5112x; 1.5112x over previous
//
#include <hip/hip_runtime.h>
#include <stdint.h>
#include <stddef.h>

#define TT 1024
#define BB 64
#define HH 1024
#define II 1024

typedef __attribute__((ext_vector_type(8))) short s16x8;
typedef __attribute__((ext_vector_type(4))) float f32x4;
typedef __attribute__((ext_vector_type(2))) unsigned u32x2;

// ---- workspace layout (bytes) ---- (proven footprint, <= 266240)
// 512  : flags[8][64] u32   (per group: words 0..15 used; 256 B stride)
// 4096 : ring: group*32768 + slot*16384 + row*2048 + feat*2
//        (8 groups, 2 slots, 8 rows, 1024 bf16 features)
#define WS_FLAGS 512
#define WS_RING  4096

static __device__ __forceinline__ unsigned short f2bf(float f) {
    union { float f; unsigned int u; } v; v.f = f;
    return (unsigned short)((v.u + 0x7fffu + ((v.u >> 16) & 1u)) >> 16);
}

static __device__ __forceinline__ s16x8 pack8(float4 a, float4 b) {
    s16x8 v;
    v[0] = (short)f2bf(a.x); v[1] = (short)f2bf(a.y);
    v[2] = (short)f2bf(a.z); v[3] = (short)f2bf(a.w);
    v[4] = (short)f2bf(b.x); v[5] = (short)f2bf(b.y);
    v[6] = (short)f2bf(b.z); v[7] = (short)f2bf(b.w);
    return v;
}

static __device__ __forceinline__ f32x4 zero4() {
    f32x4 v = {0.f, 0.f, 0.f, 0.f};
    return v;
}

// Device-coherent-point access (r3/r5/r9/r10-proven): sc0 sc1 = bypass L1+L2.
static __device__ __forceinline__ s16x8 ld16_sc01(const void* p) {
    s16x8 v;
    asm volatile("global_load_dwordx4 %0, %1, off sc0 sc1" : "=v"(v) : "v"(p));
    return v;
}
static __device__ __forceinline__ unsigned ld4_sc01_wait(const void* p) {
    unsigned v;
    asm volatile("global_load_dword %0, %1, off sc0 sc1\n\ts_waitcnt vmcnt(0)"
                 : "=v"(v) : "v"(p) : "memory");
    return v;
}
static __device__ __forceinline__ void st8_sc01(void* p, u32x2 v) {
    asm volatile("global_store_dwordx2 %0, %1, off sc0 sc1" :: "v"(p), "v"(v) : "memory");
}
#define WAITV(n) do { asm volatile("s_waitcnt vmcnt(" #n ")" ::: "memory"); \
                      __builtin_amdgcn_sched_barrier(0); } while (0)

// ---------------------------------------------------------------------------
// Kernel 0: zero the control region (flags) each launch.
// ---------------------------------------------------------------------------
__global__ void init_ws(unsigned int* w) {
    for (int i = threadIdx.x; i < 640; i += 256)
        __hip_atomic_store(&w[i], 0u, __ATOMIC_RELAXED, __HIP_MEMORY_SCOPE_AGENT);
}

// ---------------------------------------------------------------------------
// Kernel 1: xw = x @ W_ih^T + b_ih + b_hh -> d_out states area. Structure
// unchanged; launch_bounds min-waves 2->3 for +50% occupancy (fp32 staging
// is latency-bound).
// ---------------------------------------------------------------------------
__global__ __launch_bounds__(256, 3) void xw_gemm(
    const float* __restrict__ X,
    const float* __restrict__ Wih,
    const float* __restrict__ bih,
    const float* __restrict__ bhh,
    float* __restrict__ out)
{
    __shared__ unsigned short As[128 * 64];
    __shared__ unsigned short Bs[128 * 64];

    const int tid  = threadIdx.x;
    const int lane = tid & 63;
    const int wid  = tid >> 6;
    const int bm = blockIdx.x >> 3;
    const int bn = blockIdx.x & 7;
    const size_t m0 = (size_t)bm * 128;
    const int n0 = bn * 128;
    const int wm = (wid >> 1) * 64;
    const int wn = (wid & 1) * 64;

    f32x4 acc[4][4];
#pragma unroll
    for (int i = 0; i < 4; ++i)
#pragma unroll
        for (int jj = 0; jj < 4; ++jj) acc[i][jj] = zero4();

    const int srow  = tid >> 1;
    const int shalf = tid & 1;
    const float* xp = X   + (m0 + srow) * (size_t)II + shalf * 32;
    const float* wp = Wih + (size_t)(n0 + srow) * II + shalf * 32;

    for (int kt = 0; kt < II / 64; ++kt) {
#pragma unroll
        for (int i = 0; i < 4; ++i) {
            float4 a0 = *(const float4*)(xp + i * 8);
            float4 a1 = *(const float4*)(xp + i * 8 + 4);
            float4 b0 = *(const float4*)(wp + i * 8);
            float4 b1 = *(const float4*)(wp + i * 8 + 4);
            const int c = shalf * 4 + i;
            const int cw = (c ^ (srow & 7)) << 3;
            *(s16x8*)&As[srow * 64 + cw] = pack8(a0, a1);
            *(s16x8*)&Bs[srow * 64 + cw] = pack8(b0, b1);
        }
        __syncthreads();

#pragma unroll
        for (int kk = 0; kk < 2; ++kk) {
            s16x8 af[4], bf[4];
            const int cs = kk * 4 + (lane >> 4);
#pragma unroll
            for (int mi = 0; mi < 4; ++mi) {
                const int r = wm + mi * 16 + (lane & 15);
                af[mi] = *(const s16x8*)&As[r * 64 + ((cs ^ (r & 7)) << 3)];
            }
#pragma unroll
            for (int ni = 0; ni < 4; ++ni) {
                const int r = wn + ni * 16 + (lane & 15);
                bf[ni] = *(const s16x8*)&Bs[r * 64 + ((cs ^ (r & 7)) << 3)];
            }
#pragma unroll
            for (int mi = 0; mi < 4; ++mi)
#pragma unroll
                for (int ni = 0; ni < 4; ++ni)
                    acc[mi][ni] = __builtin_amdgcn_mfma_f32_16x16x32_bf16(
                        af[mi], bf[ni], acc[mi][ni], 0, 0, 0);
        }
        __syncthreads();
        xp += 64; wp += 64;
    }

#pragma unroll
    for (int ni = 0; ni < 4; ++ni) {
        const int col = n0 + wn + ni * 16 + (lane & 15);
        const float bias = bih[col] + bhh[col];
#pragma unroll
        for (int mi = 0; mi < 4; ++mi) {
            const size_t row = m0 + wm + mi * 16 + ((lane >> 4) << 2);
#pragma unroll
            for (int r = 0; r < 4; ++r)
                out[(row + r) * (size_t)HH + col] = acc[mi][ni][r] + bias;
        }
    }
}

// ---------------------------------------------------------------------------
// Kernel 2: persistent scan (r10 protocol, 8 small groups). 128 blocks x
// 256 thr (4 waves). 8 groups x 16 blocks; group owns batch rows [8g,8g+8);
// block = 64 features (4 waves x 16, W in 128 VGPR/wave as A-frags).
// D = W*hr: lane owns 1 batch row (bl<8 valid) x 4 consecutive features.
// Per step: all-lane poll of 16 per-block flags (coalesced bypass dword) ->
// cooperative 16 KB stage (sc0sc1, counted vmcnt) into XOR-swizzled LDS ->
// syncthreads -> 32x(ds_read_b128+MFMA)/wave -> tanh -> float4 states + 8B
// ring -> vmcnt(0) -> syncthreads -> publish block flag (agent atomic).
// ---------------------------------------------------------------------------
__global__ __launch_bounds__(256, 1) void rnn_scan(
    const float* __restrict__ Whh,
    float* __restrict__ out,
    void* __restrict__ ws)
{
    __shared__ unsigned short Hl[8 * 1024];   // 16 KiB staged hr tile

    const int tid  = threadIdx.x;
    const int lane = tid & 63;
    const int wid  = tid >> 6;
    const int g  = blockIdx.x >> 4;     // 0..7 batch group (8 rows)
    const int sl = blockIdx.x & 15;     // 0..15 feature slice (64 feats)

    const int jb = sl * 64 + wid * 16;            // wave's 16-feature block
    const int kg = lane >> 4;                     // k-subchunk / feat quarter

    // ---- one-time: wave's 16 W_hh rows -> 128 VGPRs of A-fragments ----
    s16x8 afr[32];
    {
        const float* wr = Whh + (size_t)(jb + (lane & 15)) * HH + kg * 8;
#pragma unroll
        for (int c = 0; c < 32; ++c) {
            float4 p0 = *(const float4*)(wr + c * 32);
            float4 p1 = *(const float4*)(wr + c * 32 + 4);
            afr[c] = pack8(p0, p1);
        }
    }

    unsigned* fl = (unsigned*)((char*)ws + WS_FLAGS) + g * 64;
    char* rg = (char*)ws + WS_RING + (size_t)g * 32768;

    // staging role: row tid>>5 (0..7), 16B seg tid&31; 4 chunks/thread
    const int srow = tid >> 5;
    const int sseg = tid & 31;
    const char* sbase0 = rg + srow * 2048 + sseg * 16;   // slot 0
    const char* sbase1 = sbase0 + 16384;                  // slot 1

    // output mapping (D = W*hr): lane&15 = batch col; only bl<8 valid
    const int bl   = lane & 15;
    const int blv  = bl & 7;                      // clamped (in-bounds reads)
    const int act  = bl < 8;                      // this lane owns a real row
    const int b    = g * 8 + blv;                 // global batch row
    const int f0   = jb + kg * 4;                 // first of 4 features
    const int hrow = blv;                         // LDS row for B-frag reads

    float hprev[4];

    // ---- t = 0: h = tanh(xw); hr_1 = 0.5*h -> slot 1 ----
    {
        const size_t idx = ((size_t)b * TT) * HH + f0;
        float4 xw4 = *(const float4*)(out + idx);
        float4 st;
        st.x = tanhf(xw4.x); st.y = tanhf(xw4.y);
        st.z = tanhf(xw4.z); st.w = tanhf(xw4.w);
        hprev[0] = st.x; hprev[1] = st.y; hprev[2] = st.z; hprev[3] = st.w;
        if (act) {
            *(float4*)(out + idx) = st;
            u32x2 pk;
            pk[0] = (unsigned)f2bf(0.5f * st.x) | ((unsigned)f2bf(0.5f * st.y) << 16);
            pk[1] = (unsigned)f2bf(0.5f * st.z) | ((unsigned)f2bf(0.5f * st.w) << 16);
            st8_sc01(rg + 16384 + blv * 2048 + f0 * 2, pk);
        }
    }
    asm volatile("s_waitcnt vmcnt(0)" ::: "memory");
    __syncthreads();
    if (tid == 0)
        __hip_atomic_store(&fl[sl], 1u, __ATOMIC_RELAXED, __HIP_MEMORY_SCOPE_AGENT);

#pragma unroll 1
    for (int t = 1; t < TT; ++t) {
        // ---- xw prefetch: issued now, drained during the first poll iter ----
        const size_t xidx = ((size_t)b * TT + t) * HH + f0;
        float4 xw4 = *(const float4*)(out + xidx);

        // ---- poll 16 per-block flags (coalesced bypass, 1 line/wave) ----
        {
            const unsigned* myp = fl + (lane & 15);
            for (;;) {
                unsigned v = ld4_sc01_wait(myp);
                if (__all((int)(v >= (unsigned)t))) break;
                __builtin_amdgcn_s_sleep(1);
            }
            asm volatile("" ::: "memory");
            __builtin_amdgcn_sched_barrier(0);
        }

        // ---- cooperative stage: 16 KB tile, once per block, coalesced ----
        {
            const char* sp = (t & 1) ? sbase1 : sbase0;
            s16x8 v[4];
#pragma unroll
            for (int i = 0; i < 4; ++i) v[i] = ld16_sc01(sp + i * 512);
#pragma unroll
            for (int i = 0; i < 4; ++i) {
                if (i == 0)      { WAITV(3); }
                else if (i == 1) { WAITV(2); }
                else if (i == 2) { WAITV(1); }
                else             { WAITV(0); }
                const int c = sseg + i * 32;                  // chunk 0..127
                *(s16x8*)&Hl[srow * 1024 + ((c ^ (srow & 7)) << 3)] = v[i];
            }
        }
        __syncthreads();

        // ---- 32 x (ds_read_b128 B-frag + MFMA with VGPR A=W) ----
        f32x4 acc[4];
#pragma unroll
        for (int i = 0; i < 4; ++i) acc[i] = zero4();
#pragma unroll
        for (int kb = 0; kb < 4; ++kb) {
            s16x8 h8[8];
#pragma unroll
            for (int ki = 0; ki < 8; ++ki) {
                const int cs = (kb * 8 + ki) * 4 + kg;
                h8[ki] = *(const s16x8*)&Hl[hrow * 1024 + ((cs ^ (hrow & 7)) << 3)];
            }
#pragma unroll
            for (int ki = 0; ki < 8; ++ki)
                acc[ki & 3] = __builtin_amdgcn_mfma_f32_16x16x32_bf16(
                    afr[kb * 8 + ki], h8[ki], acc[ki & 3], 0, 0, 0);
        }
        f32x4 accT = acc[0] + acc[1] + acc[2] + acc[3];

        // ---- epilogue: tanh, float4 state store, packed 8B ring store ----
        {
            float hn[4];
#pragma unroll
            for (int r = 0; r < 4; ++r)
                hn[r] = tanhf(accT[r] + ((const float*)&xw4)[r]);
            if (act) {
                float4 st; st.x = hn[0]; st.y = hn[1]; st.z = hn[2]; st.w = hn[3];
                *(float4*)(out + xidx) = st;
                if (t == TT - 1) {
                    *(float4*)(out + (size_t)BB * TT * HH + (size_t)b * HH + f0) = st;
                } else {
                    u32x2 pk;
                    pk[0] = (unsigned)f2bf(0.5f * (hn[0] + hprev[0])) |
                            ((unsigned)f2bf(0.5f * (hn[1] + hprev[1])) << 16);
                    pk[1] = (unsigned)f2bf(0.5f * (hn[2] + hprev[2])) |
                            ((unsigned)f2bf(0.5f * (hn[3] + hprev[3])) << 16);
                    char* rw = rg + (size_t)((t + 1) & 1) * 16384;
                    st8_sc01(rw + blv * 2048 + f0 * 2, pk);
                }
            }
#pragma unroll
            for (int r = 0; r < 4; ++r) hprev[r] = hn[r];
        }
        if (t < TT - 1) {
            asm volatile("s_waitcnt vmcnt(0)" ::: "memory");
            __syncthreads();   // all waves' ring stores drained; LDS reads done
            if (tid == 0)
                __hip_atomic_store(&fl[sl], (unsigned)(t + 1),
                                   __ATOMIC_RELAXED, __HIP_MEMORY_SCOPE_AGENT);
        }
    }
}

// ---------------------------------------------------------------------------
extern "C" void kernel_launch(void* const* d_in, const int* in_sizes, int n_in,
                              void* d_out, int out_size, void* d_ws, size_t ws_size,
                              hipStream_t stream)
{
    const float* X   = (const float*)d_in[0];
    const float* Wih = (const float*)d_in[1];
    const float* Whh = (const float*)d_in[2];
    const float* bih = (const float*)d_in[3];
    const float* bhh = (const float*)d_in[4];
    float* out = (float*)d_out;

    init_ws<<<dim3(1), dim3(256), 0, stream>>>((unsigned int*)d_ws);
    xw_gemm<<<dim3(4096), dim3(256), 0, stream>>>(X, Wih, bih, bhh, out);
    rnn_scan<<<dim3(128), dim3(256), 0, stream>>>(Whh, out, d_ws);
}